// Round 1
// baseline (4902.772 us; speedup 1.0000x reference)
//
#include <hip/hip_runtime.h>

#define SEQ 1024
#define ISZ 6
#define HSZ 128
#define PRED 50
#define MROW 16

using f32x4  = __attribute__((ext_vector_type(4))) float;
using bf16x8 = __attribute__((ext_vector_type(8))) short;

__device__ __forceinline__ short f2bf(float f){
  union { float f; unsigned u; } v; v.f = f;
  unsigned r = v.u + 0x7FFFu + ((v.u >> 16) & 1u);
  return (short)(r >> 16);
}
__device__ __forceinline__ float sigf(float x){
  float e = __builtin_amdgcn_exp2f(x * -1.4426950408889634f);
  return __builtin_amdgcn_rcpf(1.0f + e);
}
__device__ __forceinline__ float tanhf_(float x){
  float e = __builtin_amdgcn_exp2f(x * 2.8853900817779268f);
  return 1.0f - 2.0f * __builtin_amdgcn_rcpf(1.0f + e);
}

// One block = 512 threads = 8 waves, one block per CU, M=16 batch rows.
// Wave w owns hidden units [16w, 16w+16) of BOTH layers (all 4 gates = 64 of
// the 512 gate columns). Weights w_hh0 / w_ih1 / w_hh1 live in VGPRs as MFMA
// B-fragments (bf16). States c0/c1 in registers (fp32); h0/h1 via swizzled,
// double-buffered LDS (bf16).
__global__ __launch_bounds__(512) void lstm_ar(
    const float* __restrict__ x,
    const float* __restrict__ w_ih0, const float* __restrict__ w_hh0,
    const float* __restrict__ b_ih0, const float* __restrict__ b_hh0,
    const float* __restrict__ w_ih1, const float* __restrict__ w_hh1,
    const float* __restrict__ b_ih1, const float* __restrict__ b_hh1,
    const float* __restrict__ fc_w, const float* __restrict__ fc_b,
    float* __restrict__ out)
{
  __shared__ short s_h0[2][MROW*HSZ];   // bf16 h0, double buffered, XOR-swizzled
  __shared__ short s_h1[2][MROW*HSZ];
  __shared__ short s_x[65*MROW*8];      // x chunk (64 steps) + slot 64 = AR "cur"
  __shared__ short s_wih0[512*8];       // w_ih0 bf16, K padded 6->8 (rest of K-tile zero)
  __shared__ float s_h1f[MROW*HSZ];     // fp32 h1 for the fc head
  __shared__ float s_fcw[ISZ*HSZ];
  __shared__ float s_fcb[8];
  __shared__ short s_zpad[8];           // 16B of zeros for padded fragments

  const int tid  = threadIdx.x;
  const int wv   = tid >> 6;
  const int lane = tid & 63;
  const int l15  = lane & 15;
  const int lq   = lane >> 4;
  const int U    = wv * 16;
  const int u    = U + l15;             // this lane's hidden unit (acc/B-frag col)
  const int row0 = blockIdx.x * MROW;

  // ---- zero / stage LDS ----
  {
    short* p0 = &s_h0[0][0];
    short* p1 = &s_h1[0][0];
    for (int i = tid; i < 2*MROW*HSZ; i += 512){ p0[i] = 0; p1[i] = 0; }
    for (int i = tid; i < 65*MROW*8; i += 512) s_x[i] = 0;
    if (tid < 8){ s_zpad[tid] = 0; s_fcb[tid] = (tid < 6) ? fc_b[tid] : 0.f; }
    for (int i = tid; i < ISZ*HSZ; i += 512) s_fcw[i] = fc_w[i];
    if (tid < 512){
      #pragma unroll
      for (int k = 0; k < 6; k++) s_wih0[tid*8 + k] = f2bf(w_ih0[tid*6 + k]);
      s_wih0[tid*8 + 6] = 0; s_wih0[tid*8 + 7] = 0;
    }
  }

  // ---- weights -> registers (bf16 B-fragments) ----
  // B-frag for 16x16x32: col n = lane&15, k = (lane>>4)*8 + i  (B[k][n] = W[n][k])
  bf16x8 whh0f[4][4], wih1f[4][4], whh1f[4][4];
  float bias0[4], bias1[4];
  #pragma unroll
  for (int g = 0; g < 4; g++){
    const int c = g*128 + u;
    bias0[g] = b_ih0[c] + b_hh0[c];
    bias1[g] = b_ih1[c] + b_hh1[c];
    #pragma unroll
    for (int kt = 0; kt < 4; kt++){
      const int off = c*HSZ + kt*32 + lq*8;
      bf16x8 r0, r1, r2;
      #pragma unroll
      for (int i = 0; i < 8; i++){
        r0[i] = f2bf(w_hh0[off + i]);
        r1[i] = f2bf(w_ih1[off + i]);
        r2[i] = f2bf(w_hh1[off + i]);
      }
      whh0f[g][kt] = r0; wih1f[g][kt] = r1; whh1f[g][kt] = r2;
    }
  }

  float c0[4] = {0.f,0.f,0.f,0.f}, c1[4] = {0.f,0.f,0.f,0.f};
  __syncthreads();

  for (int t = 0; t < SEQ + PRED; ++t){
    // ---- stage 64 timesteps of x into LDS (bf16, K-padded) ----
    if (t < SEQ && (t & 63) == 0){
      for (int i = tid; i < MROW*64*ISZ; i += 512){
        const int r   = i / (64*ISZ);
        const int rem = i % (64*ISZ);
        const int ts  = rem / ISZ;
        const int k   = rem % ISZ;
        const float v = x[(size_t)(row0 + r)*(SEQ*ISZ) + (size_t)(t + ts)*ISZ + k];
        s_x[(ts*MROW + r)*8 + k] = f2bf(v);
      }
      __syncthreads();
    }
    const int tt = (t < SEQ) ? (t & 63) : 64;
    const int pb = t & 1, qb = pb ^ 1;

    // ---- layer 0: gates = x_t @ w_ih0^T + h0 @ w_hh0^T + b0 ----
    const short* pax = (lq == 0) ? (s_x + (tt*MROW + l15)*8) : s_zpad;
    const bf16x8 ax = *(const bf16x8*)pax;

    f32x4 acc[4];
    #pragma unroll
    for (int g = 0; g < 4; g++){
      const short* pw = (lq == 0) ? (s_wih0 + (g*128 + u)*8) : s_zpad;
      const bf16x8 bw = *(const bf16x8*)pw;
      f32x4 ci; ci[0] = bias0[g]; ci[1] = bias0[g]; ci[2] = bias0[g]; ci[3] = bias0[g];
      acc[g] = __builtin_amdgcn_mfma_f32_16x16x32_bf16(ax, bw, ci, 0, 0, 0);
    }
    #pragma unroll
    for (int kt = 0; kt < 4; kt++){
      const int s = kt*4 + lq;
      const short* pa = s_h0[qb] + l15*128 + ((s ^ (l15 & 7)) << 3);
      const bf16x8 a = *(const bf16x8*)pa;
      #pragma unroll
      for (int g = 0; g < 4; g++)
        acc[g] = __builtin_amdgcn_mfma_f32_16x16x32_bf16(a, whh0f[g][kt], acc[g], 0, 0, 0);
    }
    #pragma unroll
    for (int j = 0; j < 4; j++){
      const float iv = sigf(acc[0][j]);
      const float fv = sigf(acc[1][j]);
      const float gv = tanhf_(acc[2][j]);
      const float ov = sigf(acc[3][j]);
      c0[j] = fv*c0[j] + iv*gv;
      const float h = ov * tanhf_(c0[j]);
      const int r = lq*4 + j;
      s_h0[pb][r*128 + (((u >> 3) ^ (r & 7)) << 3) + (u & 7)] = f2bf(h);
    }
    __syncthreads();

    // ---- layer 1: gates = h0_new @ w_ih1^T + h1 @ w_hh1^T + b1 ----
    #pragma unroll
    for (int g = 0; g < 4; g++){
      acc[g][0] = bias1[g]; acc[g][1] = bias1[g]; acc[g][2] = bias1[g]; acc[g][3] = bias1[g];
    }
    #pragma unroll
    for (int kt = 0; kt < 4; kt++){
      const int s = kt*4 + lq;
      const short* pa = s_h0[pb] + l15*128 + ((s ^ (l15 & 7)) << 3);
      const bf16x8 a = *(const bf16x8*)pa;
      #pragma unroll
      for (int g = 0; g < 4; g++)
        acc[g] = __builtin_amdgcn_mfma_f32_16x16x32_bf16(a, wih1f[g][kt], acc[g], 0, 0, 0);
    }
    #pragma unroll
    for (int kt = 0; kt < 4; kt++){
      const int s = kt*4 + lq;
      const short* pa = s_h1[qb] + l15*128 + ((s ^ (l15 & 7)) << 3);
      const bf16x8 a = *(const bf16x8*)pa;
      #pragma unroll
      for (int g = 0; g < 4; g++)
        acc[g] = __builtin_amdgcn_mfma_f32_16x16x32_bf16(a, whh1f[g][kt], acc[g], 0, 0, 0);
    }
    const bool dofc = (t >= SEQ - 1);
    #pragma unroll
    for (int j = 0; j < 4; j++){
      const float iv = sigf(acc[0][j]);
      const float fv = sigf(acc[1][j]);
      const float gv = tanhf_(acc[2][j]);
      const float ov = sigf(acc[3][j]);
      c1[j] = fv*c1[j] + iv*gv;
      const float h = ov * tanhf_(c1[j]);
      const int r = lq*4 + j;
      s_h1[pb][r*128 + (((u >> 3) ^ (r & 7)) << 3) + (u & 7)] = f2bf(h);
      if (dofc) s_h1f[r*128 + u] = h;
    }
    __syncthreads();

    // ---- fc head: pred = tanh(h1 @ fc_w^T + fc_b); feeds AR input ----
    if (dofc){
      if (tid < 96){
        const int r  = tid / 6;
        const int ii = tid % 6;
        const f32x4* hv = (const f32x4*)(s_h1f + r*128);
        const f32x4* wf = (const f32x4*)(s_fcw + ii*128);
        float sacc = 0.f;
        #pragma unroll
        for (int kk = 0; kk < 32; kk++){
          const f32x4 a = hv[kk], b = wf[kk];
          sacc += a[0]*b[0] + a[1]*b[1] + a[2]*b[2] + a[3]*b[3];
        }
        const float pred = tanhf_(s_fcb[ii] + sacc);
        s_x[(64*MROW + r)*8 + ii] = f2bf(pred);   // next step's input
        if (t >= SEQ)
          out[(size_t)(row0 + r)*(PRED*ISZ) + (size_t)(t - SEQ)*ISZ + ii] = pred;
      }
      __syncthreads();
    }
  }
}

extern "C" void kernel_launch(void* const* d_in, const int* in_sizes, int n_in,
                              void* d_out, int out_size, void* d_ws, size_t ws_size,
                              hipStream_t stream) {
  const float* x     = (const float*)d_in[0];
  const float* w_ih0 = (const float*)d_in[1];
  const float* w_hh0 = (const float*)d_in[2];
  const float* b_ih0 = (const float*)d_in[3];
  const float* b_hh0 = (const float*)d_in[4];
  const float* w_ih1 = (const float*)d_in[5];
  const float* w_hh1 = (const float*)d_in[6];
  const float* b_ih1 = (const float*)d_in[7];
  const float* b_hh1 = (const float*)d_in[8];
  const float* fc_w  = (const float*)d_in[9];
  const float* fc_b  = (const float*)d_in[10];
  float* out = (float*)d_out;

  const int Btot = in_sizes[0] / (SEQ * ISZ);   // 4096
  const int nblk = Btot / MROW;                 // 256

  lstm_ar<<<dim3(nblk), dim3(512), 0, stream>>>(
      x, w_ih0, w_hh0, b_ih0, b_hh0, w_ih1, w_hh1, b_ih1, b_hh1, fc_w, fc_b, out);
}

// Round 2
// 4017.883 us; speedup vs baseline: 1.2202x; 1.2202x over previous
//
#include <hip/hip_runtime.h>

#define SEQ 1024
#define ISZ 6
#define HSZ 128
#define PRED 50
#define MROW 16
#define HP   136   // h row pitch in shorts (272B) -> write quarters 16 banks apart
#define FP   132   // s_h1f row pitch in floats

using f32x4  = __attribute__((ext_vector_type(4))) float;
using bf16x8 = __attribute__((ext_vector_type(8))) short;

__device__ __forceinline__ short f2bf(float f){
  union { float f; unsigned u; } v; v.f = f;
  unsigned r = v.u + 0x7FFFu + ((v.u >> 16) & 1u);
  return (short)(r >> 16);
}
__device__ __forceinline__ float sigf(float x){
  float e = __builtin_amdgcn_exp2f(x * -1.4426950408889634f);
  return __builtin_amdgcn_rcpf(1.0f + e);
}
__device__ __forceinline__ float tanhf_(float x){
  float e = __builtin_amdgcn_exp2f(x * 2.8853900817779268f);
  return 1.0f - 2.0f * __builtin_amdgcn_rcpf(1.0f + e);
}

// One block = 512 threads = 8 waves, one block per CU, M=16 batch rows.
// Wave w owns hidden units [16w, 16w+16) of BOTH layers (all 4 gates = 64 of
// the 512 gate columns). Weights w_hh0 / w_ih1 / w_hh1 live in VGPRs as MFMA
// B-fragments (bf16). States c0/c1 in registers (fp32); h0/h1 via padded-pitch
// double-buffered LDS (bf16).
// __launch_bounds__(512, 2): 2 waves/SIMD -> 256 VGPR/wave budget, so the
// 192 weight VGPRs stay resident (round-1 run spilled them at 128).
__global__ __launch_bounds__(512, 2) void lstm_ar(
    const float* __restrict__ x,
    const float* __restrict__ w_ih0, const float* __restrict__ w_hh0,
    const float* __restrict__ b_ih0, const float* __restrict__ b_hh0,
    const float* __restrict__ w_ih1, const float* __restrict__ w_hh1,
    const float* __restrict__ b_ih1, const float* __restrict__ b_hh1,
    const float* __restrict__ fc_w, const float* __restrict__ fc_b,
    float* __restrict__ out)
{
  __shared__ short s_h0[2][MROW*HP];    // bf16 h0, double buffered, padded pitch
  __shared__ short s_h1[2][MROW*HP];
  __shared__ short s_x[65*MROW*8];      // x chunk (64 steps) + slot 64 = AR "cur"
  __shared__ short s_wih0[512*8];       // w_ih0 bf16, K padded 6->8
  __shared__ float s_h1f[MROW*FP];      // fp32 h1 for the fc head
  __shared__ float s_fcw[ISZ*HSZ];
  __shared__ float s_fcb[8];
  __shared__ short s_zpad[8];           // 16B of zeros for padded fragments

  const int tid  = threadIdx.x;
  const int wv   = tid >> 6;
  const int lane = tid & 63;
  const int l15  = lane & 15;
  const int lq   = lane >> 4;
  const int U    = wv * 16;
  const int u    = U + l15;             // this lane's hidden unit (acc/B-frag col)
  const int row0 = blockIdx.x * MROW;

  // ---- zero / stage LDS ----
  {
    short* p0 = &s_h0[0][0];
    short* p1 = &s_h1[0][0];
    for (int i = tid; i < 2*MROW*HP; i += 512){ p0[i] = 0; p1[i] = 0; }
    for (int i = tid; i < 65*MROW*8; i += 512) s_x[i] = 0;
    if (tid < 8){ s_zpad[tid] = 0; s_fcb[tid] = (tid < 6) ? fc_b[tid] : 0.f; }
    for (int i = tid; i < ISZ*HSZ; i += 512) s_fcw[i] = fc_w[i];
    {
      #pragma unroll
      for (int k = 0; k < 6; k++) s_wih0[tid*8 + k] = f2bf(w_ih0[tid*6 + k]);
      s_wih0[tid*8 + 6] = 0; s_wih0[tid*8 + 7] = 0;
    }
  }

  // ---- weights -> registers (bf16 B-fragments) ----
  // B-frag for 16x16x32: col n = lane&15, k = (lane>>4)*8 + i  (B[k][n] = W[n][k])
  bf16x8 whh0f[4][4], wih1f[4][4], whh1f[4][4];
  float bias0[4], bias1[4];
  #pragma unroll
  for (int g = 0; g < 4; g++){
    const int c = g*128 + u;
    bias0[g] = b_ih0[c] + b_hh0[c];
    bias1[g] = b_ih1[c] + b_hh1[c];
    #pragma unroll
    for (int kt = 0; kt < 4; kt++){
      const int off = c*HSZ + kt*32 + lq*8;
      bf16x8 r0, r1, r2;
      #pragma unroll
      for (int i = 0; i < 8; i++){
        r0[i] = f2bf(w_hh0[off + i]);
        r1[i] = f2bf(w_ih1[off + i]);
        r2[i] = f2bf(w_hh1[off + i]);
      }
      whh0f[g][kt] = r0; wih1f[g][kt] = r1; whh1f[g][kt] = r2;
    }
  }

  float c0[4] = {0.f,0.f,0.f,0.f}, c1[4] = {0.f,0.f,0.f,0.f};
  __syncthreads();

  for (int t = 0; t < SEQ + PRED; ++t){
    // ---- stage 64 timesteps of x into LDS (bf16, K-padded) ----
    if (t < SEQ && (t & 63) == 0){
      for (int i = tid; i < MROW*64*ISZ; i += 512){
        const int r   = i / (64*ISZ);
        const int rem = i % (64*ISZ);
        const int ts  = rem / ISZ;
        const int k   = rem % ISZ;
        const float v = x[(size_t)(row0 + r)*(SEQ*ISZ) + (size_t)(t + ts)*ISZ + k];
        s_x[(ts*MROW + r)*8 + k] = f2bf(v);
      }
      __syncthreads();
    }
    const int tt = (t < SEQ) ? (t & 63) : 64;
    const int pb = t & 1, qb = pb ^ 1;

    // ---- layer 0: gates = x_t @ w_ih0^T + h0 @ w_hh0^T + b0 ----
    const short* pax = (lq == 0) ? (s_x + (tt*MROW + l15)*8) : s_zpad;
    const bf16x8 ax = *(const bf16x8*)pax;

    f32x4 acc[4];
    #pragma unroll
    for (int g = 0; g < 4; g++){
      const short* pw = (lq == 0) ? (s_wih0 + (g*128 + u)*8) : s_zpad;
      const bf16x8 bw = *(const bf16x8*)pw;
      f32x4 ci; ci[0] = bias0[g]; ci[1] = bias0[g]; ci[2] = bias0[g]; ci[3] = bias0[g];
      acc[g] = __builtin_amdgcn_mfma_f32_16x16x32_bf16(ax, bw, ci, 0, 0, 0);
    }
    #pragma unroll
    for (int kt = 0; kt < 4; kt++){
      const int s = kt*4 + lq;
      const short* pa = s_h0[qb] + l15*HP + s*8;
      const bf16x8 a = *(const bf16x8*)pa;
      #pragma unroll
      for (int g = 0; g < 4; g++)
        acc[g] = __builtin_amdgcn_mfma_f32_16x16x32_bf16(a, whh0f[g][kt], acc[g], 0, 0, 0);
    }
    #pragma unroll
    for (int j = 0; j < 4; j++){
      const float iv = sigf(acc[0][j]);
      const float fv = sigf(acc[1][j]);
      const float gv = tanhf_(acc[2][j]);
      const float ov = sigf(acc[3][j]);
      c0[j] = fv*c0[j] + iv*gv;
      const float h = ov * tanhf_(c0[j]);
      const int r = lq*4 + j;
      s_h0[pb][r*HP + u] = f2bf(h);
    }
    __syncthreads();

    // ---- layer 1: gates = h0_new @ w_ih1^T + h1 @ w_hh1^T + b1 ----
    #pragma unroll
    for (int g = 0; g < 4; g++){
      acc[g][0] = bias1[g]; acc[g][1] = bias1[g]; acc[g][2] = bias1[g]; acc[g][3] = bias1[g];
    }
    #pragma unroll
    for (int kt = 0; kt < 4; kt++){
      const int s = kt*4 + lq;
      const short* pa = s_h0[pb] + l15*HP + s*8;
      const bf16x8 a = *(const bf16x8*)pa;
      #pragma unroll
      for (int g = 0; g < 4; g++)
        acc[g] = __builtin_amdgcn_mfma_f32_16x16x32_bf16(a, wih1f[g][kt], acc[g], 0, 0, 0);
    }
    #pragma unroll
    for (int kt = 0; kt < 4; kt++){
      const int s = kt*4 + lq;
      const short* pa = s_h1[qb] + l15*HP + s*8;
      const bf16x8 a = *(const bf16x8*)pa;
      #pragma unroll
      for (int g = 0; g < 4; g++)
        acc[g] = __builtin_amdgcn_mfma_f32_16x16x32_bf16(a, whh1f[g][kt], acc[g], 0, 0, 0);
    }
    const bool dofc = (t >= SEQ - 1);
    #pragma unroll
    for (int j = 0; j < 4; j++){
      const float iv = sigf(acc[0][j]);
      const float fv = sigf(acc[1][j]);
      const float gv = tanhf_(acc[2][j]);
      const float ov = sigf(acc[3][j]);
      c1[j] = fv*c1[j] + iv*gv;
      const float h = ov * tanhf_(c1[j]);
      const int r = lq*4 + j;
      s_h1[pb][r*HP + u] = f2bf(h);
      if (dofc) s_h1f[r*FP + u] = h;
    }
    __syncthreads();

    // ---- fc head: pred = tanh(h1 @ fc_w^T + fc_b); feeds AR input ----
    if (dofc){
      if (tid < 96){
        const int r  = tid / 6;
        const int ii = tid % 6;
        const f32x4* hv = (const f32x4*)(s_h1f + r*FP);
        const f32x4* wf = (const f32x4*)(s_fcw + ii*128);
        float sacc = 0.f;
        #pragma unroll
        for (int kk = 0; kk < 32; kk++){
          const f32x4 a = hv[kk], b = wf[kk];
          sacc += a[0]*b[0] + a[1]*b[1] + a[2]*b[2] + a[3]*b[3];
        }
        const float pred = tanhf_(s_fcb[ii] + sacc);
        s_x[(64*MROW + r)*8 + ii] = f2bf(pred);   // next step's input
        if (t >= SEQ)
          out[(size_t)(row0 + r)*(PRED*ISZ) + (size_t)(t - SEQ)*ISZ + ii] = pred;
      }
      __syncthreads();
    }
  }
}

extern "C" void kernel_launch(void* const* d_in, const int* in_sizes, int n_in,
                              void* d_out, int out_size, void* d_ws, size_t ws_size,
                              hipStream_t stream) {
  const float* x     = (const float*)d_in[0];
  const float* w_ih0 = (const float*)d_in[1];
  const float* w_hh0 = (const float*)d_in[2];
  const float* b_ih0 = (const float*)d_in[3];
  const float* b_hh0 = (const float*)d_in[4];
  const float* w_ih1 = (const float*)d_in[5];
  const float* w_hh1 = (const float*)d_in[6];
  const float* b_ih1 = (const float*)d_in[7];
  const float* b_hh1 = (const float*)d_in[8];
  const float* fc_w  = (const float*)d_in[9];
  const float* fc_b  = (const float*)d_in[10];
  float* out = (float*)d_out;

  const int Btot = in_sizes[0] / (SEQ * ISZ);   // 4096
  const int nblk = Btot / MROW;                 // 256

  lstm_ar<<<dim3(nblk), dim3(512), 0, stream>>>(
      x, w_ih0, w_hh0, b_ih0, b_hh0, w_ih1, w_hh1, b_ih1, b_hh1, fc_w, fc_b, out);
}

// Round 3
// 3698.612 us; speedup vs baseline: 1.3256x; 1.0863x over previous
//
#include <hip/hip_runtime.h>

#define SEQ 1024
#define ISZ 6
#define HSZ 128
#define PRED 50
#define MROW 16
#define HP   136   // h row pitch in shorts (272B)
#define FP   132   // s_h1f row pitch in floats

using f32x4  = __attribute__((ext_vector_type(4))) float;
using bf16x8 = __attribute__((ext_vector_type(8))) short;

__device__ __forceinline__ short f2bf(float f){
  union { float f; unsigned u; } v; v.f = f;
  unsigned r = v.u + 0x7FFFu + ((v.u >> 16) & 1u);
  return (short)(r >> 16);
}
__device__ __forceinline__ float sigf(float x){
  float e = __builtin_amdgcn_exp2f(x * -1.4426950408889634f);
  return __builtin_amdgcn_rcpf(1.0f + e);
}
__device__ __forceinline__ float tanhf_(float x){
  float e = __builtin_amdgcn_exp2f(x * 2.8853900817779268f);
  return 1.0f - 2.0f * __builtin_amdgcn_rcpf(1.0f + e);
}

// One block = 512 threads = 8 waves, one block per CU, M=16 batch rows.
// Wave w owns hidden units [16w, 16w+16) of BOTH layers. Weights w_hh0 /
// w_ih1 / w_hh1 live in VGPRs as MFMA B-fragments (bf16, 192 VGPRs/thread).
// amdgpu_waves_per_eu(2,2): exactly 2 waves/SIMD -> 256-VGPR budget. Round-2
// run proved __launch_bounds__(512,2) leaves the cap at 128 and spills all
// weight fragments to scratch (WRITE_SIZE 114MB); this pins it.
__global__ __launch_bounds__(512)
__attribute__((amdgpu_waves_per_eu(2, 2)))
void lstm_ar(
    const float* __restrict__ x,
    const float* __restrict__ w_ih0, const float* __restrict__ w_hh0,
    const float* __restrict__ b_ih0, const float* __restrict__ b_hh0,
    const float* __restrict__ w_ih1, const float* __restrict__ w_hh1,
    const float* __restrict__ b_ih1, const float* __restrict__ b_hh1,
    const float* __restrict__ fc_w, const float* __restrict__ fc_b,
    float* __restrict__ out)
{
  __shared__ short s_h0[2][MROW*HP];    // bf16 h0, double buffered, padded pitch
  __shared__ short s_h1[2][MROW*HP];
  __shared__ short s_x[65*MROW*8];      // x chunk (64 steps) + slot 64 = AR "cur"
  __shared__ short s_wih0[512*8];       // w_ih0 bf16, K padded 6->8
  __shared__ float s_h1f[MROW*FP];      // fp32 h1 for the fc head
  __shared__ float s_fcw[ISZ*HSZ];
  __shared__ float s_fcb[8];
  __shared__ short s_zpad[8];           // 16B of zeros for padded fragments

  const int tid  = threadIdx.x;
  const int wv   = tid >> 6;
  const int lane = tid & 63;
  const int l15  = lane & 15;
  const int lq   = lane >> 4;
  const int U    = wv * 16;
  const int u    = U + l15;             // this lane's hidden unit (acc/B-frag col)
  const int row0 = blockIdx.x * MROW;

  // ---- zero / stage LDS ----
  {
    short* p0 = &s_h0[0][0];
    short* p1 = &s_h1[0][0];
    for (int i = tid; i < 2*MROW*HP; i += 512){ p0[i] = 0; p1[i] = 0; }
    for (int i = tid; i < 65*MROW*8; i += 512) s_x[i] = 0;
    if (tid < 8){ s_zpad[tid] = 0; s_fcb[tid] = (tid < 6) ? fc_b[tid] : 0.f; }
    for (int i = tid; i < ISZ*HSZ; i += 512) s_fcw[i] = fc_w[i];
    {
      #pragma unroll
      for (int k = 0; k < 6; k++) s_wih0[tid*8 + k] = f2bf(w_ih0[tid*6 + k]);
      s_wih0[tid*8 + 6] = 0; s_wih0[tid*8 + 7] = 0;
    }
  }

  // ---- weights -> registers (bf16 B-fragments) ----
  // B-frag for 16x16x32: col n = lane&15, k = (lane>>4)*8 + i  (B[k][n] = W[n][k])
  bf16x8 whh0f[4][4], wih1f[4][4], whh1f[4][4];
  float bias0[4], bias1[4];
  #pragma unroll
  for (int g = 0; g < 4; g++){
    const int c = g*128 + u;
    bias0[g] = b_ih0[c] + b_hh0[c];
    bias1[g] = b_ih1[c] + b_hh1[c];
    #pragma unroll
    for (int kt = 0; kt < 4; kt++){
      const int off = c*HSZ + kt*32 + lq*8;
      bf16x8 r0, r1, r2;
      #pragma unroll
      for (int i = 0; i < 8; i++){
        r0[i] = f2bf(w_hh0[off + i]);
        r1[i] = f2bf(w_ih1[off + i]);
        r2[i] = f2bf(w_hh1[off + i]);
      }
      whh0f[g][kt] = r0; wih1f[g][kt] = r1; whh1f[g][kt] = r2;
    }
  }

  float c0[4] = {0.f,0.f,0.f,0.f}, c1[4] = {0.f,0.f,0.f,0.f};
  __syncthreads();

  for (int t = 0; t < SEQ + PRED; ++t){
    // ---- stage 64 timesteps of x into LDS (bf16, K-padded) ----
    if (t < SEQ && (t & 63) == 0){
      for (int i = tid; i < MROW*64*ISZ; i += 512){
        const int r   = i / (64*ISZ);
        const int rem = i % (64*ISZ);
        const int ts  = rem / ISZ;
        const int k   = rem % ISZ;
        const float v = x[(size_t)(row0 + r)*(SEQ*ISZ) + (size_t)(t + ts)*ISZ + k];
        s_x[(ts*MROW + r)*8 + k] = f2bf(v);
      }
      __syncthreads();
    }
    const int tt = (t < SEQ) ? (t & 63) : 64;
    const int pb = t & 1, qb = pb ^ 1;

    // ---- layer 0: gates = x_t @ w_ih0^T + h0 @ w_hh0^T + b0 ----
    const short* pax = (lq == 0) ? (s_x + (tt*MROW + l15)*8) : s_zpad;
    const bf16x8 ax = *(const bf16x8*)pax;

    f32x4 acc[4];
    #pragma unroll
    for (int g = 0; g < 4; g++){
      const short* pw = (lq == 0) ? (s_wih0 + (g*128 + u)*8) : s_zpad;
      const bf16x8 bw = *(const bf16x8*)pw;
      f32x4 ci; ci[0] = bias0[g]; ci[1] = bias0[g]; ci[2] = bias0[g]; ci[3] = bias0[g];
      acc[g] = __builtin_amdgcn_mfma_f32_16x16x32_bf16(ax, bw, ci, 0, 0, 0);
    }
    #pragma unroll
    for (int kt = 0; kt < 4; kt++){
      const int s = kt*4 + lq;
      const short* pa = s_h0[qb] + l15*HP + s*8;
      const bf16x8 a = *(const bf16x8*)pa;
      #pragma unroll
      for (int g = 0; g < 4; g++)
        acc[g] = __builtin_amdgcn_mfma_f32_16x16x32_bf16(a, whh0f[g][kt], acc[g], 0, 0, 0);
    }
    #pragma unroll
    for (int j = 0; j < 4; j++){
      const float iv = sigf(acc[0][j]);
      const float fv = sigf(acc[1][j]);
      const float gv = tanhf_(acc[2][j]);
      const float ov = sigf(acc[3][j]);
      c0[j] = fv*c0[j] + iv*gv;
      const float h = ov * tanhf_(c0[j]);
      const int r = lq*4 + j;
      s_h0[pb][r*HP + u] = f2bf(h);
    }
    __syncthreads();

    // ---- layer 1: gates = h0_new @ w_ih1^T + h1 @ w_hh1^T + b1 ----
    #pragma unroll
    for (int g = 0; g < 4; g++){
      acc[g][0] = bias1[g]; acc[g][1] = bias1[g]; acc[g][2] = bias1[g]; acc[g][3] = bias1[g];
    }
    #pragma unroll
    for (int kt = 0; kt < 4; kt++){
      const int s = kt*4 + lq;
      const short* pa = s_h0[pb] + l15*HP + s*8;
      const bf16x8 a = *(const bf16x8*)pa;
      #pragma unroll
      for (int g = 0; g < 4; g++)
        acc[g] = __builtin_amdgcn_mfma_f32_16x16x32_bf16(a, wih1f[g][kt], acc[g], 0, 0, 0);
    }
    #pragma unroll
    for (int kt = 0; kt < 4; kt++){
      const int s = kt*4 + lq;
      const short* pa = s_h1[qb] + l15*HP + s*8;
      const bf16x8 a = *(const bf16x8*)pa;
      #pragma unroll
      for (int g = 0; g < 4; g++)
        acc[g] = __builtin_amdgcn_mfma_f32_16x16x32_bf16(a, whh1f[g][kt], acc[g], 0, 0, 0);
    }
    const bool dofc = (t >= SEQ - 1);
    #pragma unroll
    for (int j = 0; j < 4; j++){
      const float iv = sigf(acc[0][j]);
      const float fv = sigf(acc[1][j]);
      const float gv = tanhf_(acc[2][j]);
      const float ov = sigf(acc[3][j]);
      c1[j] = fv*c1[j] + iv*gv;
      const float h = ov * tanhf_(c1[j]);
      const int r = lq*4 + j;
      s_h1[pb][r*HP + u] = f2bf(h);
      if (dofc) s_h1f[r*FP + u] = h;
    }
    __syncthreads();

    // ---- fc head: pred = tanh(h1 @ fc_w^T + fc_b); feeds AR input ----
    if (dofc){
      if (tid < 96){
        const int r  = tid / 6;
        const int ii = tid % 6;
        const f32x4* hv = (const f32x4*)(s_h1f + r*FP);
        const f32x4* wf = (const f32x4*)(s_fcw + ii*128);
        float sacc = 0.f;
        #pragma unroll
        for (int kk = 0; kk < 32; kk++){
          const f32x4 a = hv[kk], b = wf[kk];
          sacc += a[0]*b[0] + a[1]*b[1] + a[2]*b[2] + a[3]*b[3];
        }
        const float pred = tanhf_(s_fcb[ii] + sacc);
        s_x[(64*MROW + r)*8 + ii] = f2bf(pred);   // next step's input
        if (t >= SEQ)
          out[(size_t)(row0 + r)*(PRED*ISZ) + (size_t)(t - SEQ)*ISZ + ii] = pred;
      }
      __syncthreads();
    }
  }
}

extern "C" void kernel_launch(void* const* d_in, const int* in_sizes, int n_in,
                              void* d_out, int out_size, void* d_ws, size_t ws_size,
                              hipStream_t stream) {
  const float* x     = (const float*)d_in[0];
  const float* w_ih0 = (const float*)d_in[1];
  const float* w_hh0 = (const float*)d_in[2];
  const float* b_ih0 = (const float*)d_in[3];
  const float* b_hh0 = (const float*)d_in[4];
  const float* w_ih1 = (const float*)d_in[5];
  const float* w_hh1 = (const float*)d_in[6];
  const float* b_ih1 = (const float*)d_in[7];
  const float* b_hh1 = (const float*)d_in[8];
  const float* fc_w  = (const float*)d_in[9];
  const float* fc_b  = (const float*)d_in[10];
  float* out = (float*)d_out;

  const int Btot = in_sizes[0] / (SEQ * ISZ);   // 4096
  const int nblk = Btot / MROW;                 // 256

  lstm_ar<<<dim3(nblk), dim3(512), 0, stream>>>(
      x, w_ih0, w_hh0, b_ih0, b_hh0, w_ih1, w_hh1, b_ih1, b_hh1, fc_w, fc_b, out);
}